// Round 2
// baseline (54.042 us; speedup 1.0000x reference)
//
#include <hip/hip_runtime.h>

// FocalLoss (sigmoid focal, mean reduction), fused single kernel.
//   cls_score: [N=4, C=19, H=512, W=512] float32
//   label:     [N=4, H=512, W=512] int32
// out: scalar f32. Memory-bound: ~84 MB read. Deterministic:
// per-block partials -> last block (via atomic counter) reduces in fixed order.
// Counter in d_ws is zeroed each call by hipMemsetAsync (graph-capturable).

#define NC 19
#define IGNORE_INDEX 255
#define ALPHA 0.25f

constexpr int NBATCH = 4;
constexpr int HW = 512 * 512;               // pixels per plane
constexpr int QPP = HW / 4;                 // quads per plane = 65536
constexpr int NQUADS = NBATCH * QPP;        // 262144
constexpr int BLOCK = 256;
constexpr int GRID = NQUADS / BLOCK;        // 1024, exact
constexpr float INV_TOTAL = 1.0f / (float)(NBATCH * NC * HW);

__device__ __forceinline__ float block_reduce(float v, float* smem) {
    #pragma unroll
    for (int off = 32; off > 0; off >>= 1)
        v += __shfl_down(v, off, 64);
    const int lane = threadIdx.x & 63;
    const int wid  = threadIdx.x >> 6;
    __syncthreads();                       // smem may be reused across calls
    if (lane == 0) smem[wid] = v;
    __syncthreads();
    float s = 0.0f;
    if (threadIdx.x == 0) {
        #pragma unroll
        for (int i = 0; i < BLOCK / 64; ++i) s += smem[i];
    }
    return s;  // valid in thread 0 only
}

__global__ __launch_bounds__(BLOCK) void focal_fused(
        const float* __restrict__ x,
        const int*   __restrict__ label,
        float*       __restrict__ partial,
        unsigned int* __restrict__ counter,
        float*       __restrict__ out) {
    const int q  = blockIdx.x * blockDim.x + threadIdx.x;   // quad index
    const int n  = q >> 16;                                  // q / QPP (65536)
    const int pq = q & (QPP - 1);

    const int4 l4 = *reinterpret_cast<const int4*>(label + (size_t)n * HW + (size_t)pq * 4);
    const int lab[4] = {l4.x, l4.y, l4.z, l4.w};
    bool valid[4];
    #pragma unroll
    for (int j = 0; j < 4; ++j)
        valid[j] = (lab[j] >= 0) && (lab[j] != IGNORE_INDEX);

    const float* base = x + (size_t)n * NC * HW + (size_t)pq * 4;

    // Hoist all 19 channel loads so they are all in flight together.
    float4 v[NC];
    #pragma unroll
    for (int c = 0; c < NC; ++c)
        v[c] = *reinterpret_cast<const float4*>(base + (size_t)c * HW);

    float acc = 0.0f;
    #pragma unroll
    for (int c = 0; c < NC; ++c) {
        const float xs[4] = {v[c].x, v[c].y, v[c].z, v[c].w};
        #pragma unroll
        for (int j = 0; j < 4; ++j) {
            const float xv = xs[j];
            const bool  t  = (lab[j] == c);
            const float d  = t ? (1.0f - xv) : xv;
            const float w  = ALPHA * d * d;
            // bce_with_logits: max(x,0) - x*t + log1p(exp(-|x|))
            const float sp  = __logf(1.0f + __expf(-fabsf(xv)));
            const float bce = fmaxf(xv, 0.0f) - (t ? xv : 0.0f) + sp;
            acc += valid[j] ? bce * w : 0.0f;
        }
    }

    __shared__ float smem[BLOCK / 64];
    const float s = block_reduce(acc, smem);

    __shared__ bool is_last;
    if (threadIdx.x == 0) {
        partial[blockIdx.x] = s;
        __threadfence();                               // publish partial
        const unsigned int old = atomicAdd(counter, 1u);
        is_last = (old == GRID - 1);
    }
    __syncthreads();

    if (is_last) {
        __threadfence();                               // acquire all partials
        float a2 = 0.0f;
        for (int i = threadIdx.x; i < GRID; i += BLOCK)
            a2 += partial[i];
        const float s2 = block_reduce(a2, smem);
        if (threadIdx.x == 0) out[0] = s2 * INV_TOTAL; // LOSS_WEIGHT == 1.0
    }
}

extern "C" void kernel_launch(void* const* d_in, const int* in_sizes, int n_in,
                              void* d_out, int out_size, void* d_ws, size_t ws_size,
                              hipStream_t stream) {
    const float* cls_score = (const float*)d_in[0];
    const int*   label     = (const int*)d_in[1];
    float* out      = (float*)d_out;
    float* partial  = (float*)d_ws;                       // GRID floats
    unsigned int* counter = (unsigned int*)((char*)d_ws + GRID * sizeof(float));

    hipMemsetAsync(counter, 0, sizeof(unsigned int), stream);
    focal_fused<<<GRID, BLOCK, 0, stream>>>(cls_score, label, partial, counter, out);
}

// Round 3
// 27.845 us; speedup vs baseline: 1.9408x; 1.9408x over previous
//
#include <hip/hip_runtime.h>

// FocalLoss (sigmoid focal, mean reduction).
//   cls_score: [N=4, C=19, H=512, W=512] float32
//   label:     [N=4, H=512, W=512] int32
// out: scalar f32.
// Two-kernel deterministic reduction (R1 structure — measured faster than
// fused last-block). R3 change: 2 pixels/thread -> 524288 threads = full
// 32 waves/CU occupancy to overlap the ~14us of VALU (exp/log) with memory.

#define NC 19
#define IGNORE_INDEX 255
#define ALPHA 0.25f

constexpr int NBATCH = 4;
constexpr int HW = 512 * 512;                 // pixels per plane
constexpr int PPP = HW / 2;                   // pairs per plane = 131072
constexpr int NPAIRS = NBATCH * PPP;          // 524288
constexpr int BLOCK = 256;
constexpr int GRID = NPAIRS / BLOCK;          // 2048, exact
constexpr float INV_TOTAL = 1.0f / (float)(NBATCH * NC * HW);

__device__ __forceinline__ float block_reduce(float v, float* smem) {
    #pragma unroll
    for (int off = 32; off > 0; off >>= 1)
        v += __shfl_down(v, off, 64);
    const int lane = threadIdx.x & 63;
    const int wid  = threadIdx.x >> 6;
    if (lane == 0) smem[wid] = v;
    __syncthreads();
    float s = 0.0f;
    if (threadIdx.x == 0) {
        #pragma unroll
        for (int i = 0; i < BLOCK / 64; ++i) s += smem[i];
    }
    return s;  // valid in thread 0 only
}

__global__ __launch_bounds__(BLOCK) void focal_partial(
        const float* __restrict__ x,
        const int*   __restrict__ label,
        float*       __restrict__ partial) {
    const int p  = blockIdx.x * blockDim.x + threadIdx.x;  // pair index
    const int n  = p >> 17;                                // p / PPP
    const int pp = p & (PPP - 1);

    const int2 l2 = *reinterpret_cast<const int2*>(label + (size_t)n * HW + (size_t)pp * 2);
    const int lab0 = l2.x, lab1 = l2.y;
    const bool val0 = (lab0 >= 0) && (lab0 != IGNORE_INDEX);
    const bool val1 = (lab1 >= 0) && (lab1 != IGNORE_INDEX);

    const float* base = x + (size_t)n * NC * HW + (size_t)pp * 2;

    float acc = 0.0f;
    for (int c = 0; c < NC; ++c) {
        const float2 v = *reinterpret_cast<const float2*>(base + (size_t)c * HW);
        {
            const float xv = v.x;
            const bool  t  = (lab0 == c);
            const float d  = t ? (1.0f - xv) : xv;
            float w        = ALPHA * d * d;
            w              = val0 ? w : 0.0f;
            const float sp  = __logf(1.0f + __expf(-fabsf(xv)));
            const float bce = fmaxf(xv, 0.0f) - (t ? xv : 0.0f) + sp;
            acc = fmaf(bce, w, acc);
        }
        {
            const float xv = v.y;
            const bool  t  = (lab1 == c);
            const float d  = t ? (1.0f - xv) : xv;
            float w        = ALPHA * d * d;
            w              = val1 ? w : 0.0f;
            const float sp  = __logf(1.0f + __expf(-fabsf(xv)));
            const float bce = fmaxf(xv, 0.0f) - (t ? xv : 0.0f) + sp;
            acc = fmaf(bce, w, acc);
        }
    }

    __shared__ float smem[BLOCK / 64];
    const float s = block_reduce(acc, smem);
    if (threadIdx.x == 0) partial[blockIdx.x] = s;
}

__global__ __launch_bounds__(BLOCK) void focal_finalize(
        const float* __restrict__ partial,
        float*       __restrict__ out) {
    float acc = 0.0f;
    for (int i = threadIdx.x; i < GRID; i += BLOCK)
        acc += partial[i];
    __shared__ float smem[BLOCK / 64];
    const float s = block_reduce(acc, smem);
    if (threadIdx.x == 0) out[0] = s * INV_TOTAL;  // LOSS_WEIGHT == 1.0
}

extern "C" void kernel_launch(void* const* d_in, const int* in_sizes, int n_in,
                              void* d_out, int out_size, void* d_ws, size_t ws_size,
                              hipStream_t stream) {
    const float* cls_score = (const float*)d_in[0];
    const int*   label     = (const int*)d_in[1];
    float* out     = (float*)d_out;
    float* partial = (float*)d_ws;   // GRID floats = 8 KB

    focal_partial<<<GRID, BLOCK, 0, stream>>>(cls_score, label, partial);
    focal_finalize<<<1, BLOCK, 0, stream>>>(partial, out);
}